// Round 1
// baseline (339.032 us; speedup 1.0000x reference)
//
#include <hip/hip_runtime.h>

#define NREZ 256
#define NB 8
#define NA 180

// Transpose each batch image: imgT[b][x][y] = img[b][y][x]
__global__ __launch_bounds__(256) void transpose_kernel(const float* __restrict__ img,
                                                        float* __restrict__ imgT) {
    __shared__ float tile[32][33];
    const int b = blockIdx.z;
    const int x0 = blockIdx.x * 32;
    const int y0 = blockIdx.y * 32;
    const int tx = threadIdx.x;  // 0..31
    const int ty = threadIdx.y;  // 0..7
    const float* src = img + (size_t)b * NREZ * NREZ;
    float* dst = imgT + (size_t)b * NREZ * NREZ;
#pragma unroll
    for (int i = 0; i < 32; i += 8) {
        tile[ty + i][tx] = src[(y0 + ty + i) * NREZ + (x0 + tx)];
    }
    __syncthreads();
#pragma unroll
    for (int i = 0; i < 32; i += 8) {
        dst[(x0 + ty + i) * NREZ + (y0 + tx)] = tile[tx][ty + i];
    }
}

// One block = one angle x 32 detector bins. Each wave: 8 s-values x 8 t-phases
// (2D lane patch -> compact image footprint per gather). Each lane accumulates
// all 8 batch images (shared addresses/weights), then butterfly-reduce over
// the t-phase lanes.
__global__ __launch_bounds__(256) void radon_kernel(const float* __restrict__ img,
                                                    const float* __restrict__ imgT,
                                                    const float* __restrict__ angles,
                                                    float* __restrict__ out,
                                                    int useT) {
    const int a = blockIdx.x;
    const int tid = threadIdx.x;
    const int wave = tid >> 6;
    const int lane = tid & 63;
    const int s_sub = lane & 7;
    const int t_sub = lane >> 3;
    const int sIdx = blockIdx.y * 32 + wave * 8 + s_sub;

    const float c = (NREZ - 1) * 0.5f;
    float sn, cs;
    sincosf(angles[a], &sn, &cs);

    // choose the image layout whose unit-stride axis moves fastest with s
    const bool transposed = useT && (fabsf(sn) > fabsf(cs));
    const float* base = transposed ? imgT : img;

    const float s = (float)sIdx - c;
    float acc[NB];
#pragma unroll
    for (int b = 0; b < NB; ++b) acc[b] = 0.f;

    for (int j = 0; j < NREZ / 8; ++j) {
        const float tt = (float)(t_sub + 8 * j) - c;
        const float x = s * cs - tt * sn + c;
        const float y = s * sn + tt * cs + c;
        const float u = transposed ? y : x;   // unit-stride (column) coordinate
        const float v = transposed ? x : y;   // row coordinate
        const float uf = floorf(u), vf = floorf(v);
        const int u0 = (int)uf, v0 = (int)vf;
        if (u0 < -1 || u0 >= NREZ || v0 < -1 || v0 >= NREZ) continue;  // all 4 corners OOB
        const float wu = u - uf, wv = v - vf;
        const bool iu0 = (u0 >= 0);
        const bool iu1 = (u0 + 1 <= NREZ - 1);
        const bool iv0 = (v0 >= 0);
        const bool iv1 = (v0 + 1 <= NREZ - 1);
        const float w00 = (1.f - wu) * (1.f - wv) * ((iu0 && iv0) ? 1.f : 0.f);
        const float w10 = wu * (1.f - wv) * ((iu1 && iv0) ? 1.f : 0.f);
        const float w01 = (1.f - wu) * wv * ((iu0 && iv1) ? 1.f : 0.f);
        const float w11 = wu * wv * ((iu1 && iv1) ? 1.f : 0.f);
        const int u0c = min(max(u0, 0), NREZ - 1);
        const int u1c = min(u0 + 1, NREZ - 1);
        const int v0c = min(max(v0, 0), NREZ - 1);
        const int v1c = min(v0 + 1, NREZ - 1);
        const int a00 = v0c * NREZ + u0c;
        const int a10 = v0c * NREZ + u1c;
        const int a01 = v1c * NREZ + u0c;
        const int a11 = v1c * NREZ + u1c;
#pragma unroll
        for (int b = 0; b < NB; ++b) {
            const float* p = base + b * (NREZ * NREZ);
            acc[b] += w00 * p[a00] + w10 * p[a10] + w01 * p[a01] + w11 * p[a11];
        }
    }

    // reduce across t-phase lanes (lane bits 3..5)
#pragma unroll
    for (int b = 0; b < NB; ++b) {
        float v = acc[b];
        v += __shfl_xor(v, 8);
        v += __shfl_xor(v, 16);
        v += __shfl_xor(v, 32);
        acc[b] = v;
    }

    if (t_sub == 0) {
#pragma unroll
        for (int b = 0; b < NB; ++b) {
            out[(b * NA + a) * NREZ + sIdx] = acc[b];
        }
    }
}

extern "C" void kernel_launch(void* const* d_in, const int* in_sizes, int n_in,
                              void* d_out, int out_size, void* d_ws, size_t ws_size,
                              hipStream_t stream) {
    (void)in_sizes; (void)n_in; (void)out_size;
    const float* imgs = (const float*)d_in[0];
    const float* angles = (const float*)d_in[1];
    float* out = (float*)d_out;

    const size_t imgBytes = (size_t)NB * NREZ * NREZ * sizeof(float);
    const int useT = (ws_size >= imgBytes) ? 1 : 0;
    float* imgT = (float*)d_ws;

    if (useT) {
        dim3 tgrid(NREZ / 32, NREZ / 32, NB);
        transpose_kernel<<<tgrid, dim3(32, 8), 0, stream>>>(imgs, imgT);
    }
    radon_kernel<<<dim3(NA, NREZ / 32), 256, 0, stream>>>(
        imgs, useT ? imgT : imgs, angles, out, useT);
}

// Round 2
// 125.400 us; speedup vs baseline: 2.7036x; 2.7036x over previous
//
#include <hip/hip_runtime.h>

#define NREZ 256
#define NB 8
#define NA 180

__device__ __forceinline__ void fma4(float4& acc, float w, const float4 v) {
    acc.x = fmaf(w, v.x, acc.x);
    acc.y = fmaf(w, v.y, acc.y);
    acc.z = fmaf(w, v.z, acc.z);
    acc.w = fmaf(w, v.w, acc.w);
}

// Build batch-interleaved layout: inter[(y*256+x)*8 + b] = img[b][y][x]
// and (optionally) the transposed copy interT[(x*256+y)*8 + b].
__global__ __launch_bounds__(256) void build_interleaved(
    const float* __restrict__ img, float* __restrict__ inter,
    float* __restrict__ interT, int buildT) {
    const int p = blockIdx.x * 256 + threadIdx.x;  // pixel id = y*256+x
    const int y = p >> 8, x = p & 255;
    float v[NB];
#pragma unroll
    for (int b = 0; b < NB; ++b) v[b] = img[b * (NREZ * NREZ) + p];
#pragma unroll
    for (int b = 0; b < NB; ++b) inter[(size_t)p * NB + b] = v[b];
    if (buildT) {
#pragma unroll
        for (int b = 0; b < NB; ++b) interT[((size_t)x * NREZ + y) * NB + b] = v[b];
    }
}

// MODE 0: interleaved + per-angle transpose trick (needs 4MB ws)
// MODE 1: interleaved only (needs 2MB ws)
// MODE 2: plain scalar fallback (no ws)
template <int MODE>
__global__ __launch_bounds__(256) void radon_kernel(
    const float* __restrict__ imgPlain,
    const float4* __restrict__ inter,
    const float4* __restrict__ interT,
    const float* __restrict__ angles,
    float* __restrict__ out) {
    const int a = blockIdx.x;
    const int tid = threadIdx.x;
    const int wave = tid >> 6;
    const int lane = tid & 63;
    const int s_sub = lane & 7;   // 8 s-values fast
    const int t_sub = lane >> 3;  // 8 t-phases
    const int sIdx = blockIdx.y * 32 + wave * 8 + s_sub;

    const float c = (NREZ - 1) * 0.5f;
    float sn, cs;
    sincosf(angles[a], &sn, &cs);

    const bool transposed = (MODE == 0) && (fabsf(sn) > fabsf(cs));
    const float4* __restrict__ base4 = transposed ? interT : inter;

    const float s = (float)sIdx - c;
    float4 accLo = {0.f, 0.f, 0.f, 0.f};
    float4 accHi = {0.f, 0.f, 0.f, 0.f};
    float accP[NB];
#pragma unroll
    for (int b = 0; b < NB; ++b) accP[b] = 0.f;

    for (int j = 0; j < NREZ / 8; ++j) {
        const float tt = (float)(t_sub + 8 * j) - c;
        const float x = s * cs - tt * sn + c;
        const float y = s * sn + tt * cs + c;
        const float u = transposed ? y : x;  // unit-stride coordinate
        const float v = transposed ? x : y;  // row coordinate
        const float uf = floorf(u), vf = floorf(v);
        const int u0 = (int)uf, v0 = (int)vf;
        if (u0 < -1 || u0 >= NREZ || v0 < -1 || v0 >= NREZ) continue;  // whole footprint OOB
        const float wu = u - uf, wv = v - vf;
        const bool iu0 = (u0 >= 0);
        const bool iu1 = (u0 + 1 <= NREZ - 1);
        const bool iv0 = (v0 >= 0);
        const bool iv1 = (v0 + 1 <= NREZ - 1);
        const float w00 = (1.f - wu) * (1.f - wv) * ((iu0 && iv0) ? 1.f : 0.f);
        const float w10 = wu * (1.f - wv) * ((iu1 && iv0) ? 1.f : 0.f);
        const float w01 = (1.f - wu) * wv * ((iu0 && iv1) ? 1.f : 0.f);
        const float w11 = wu * wv * ((iu1 && iv1) ? 1.f : 0.f);
        const int u0c = min(max(u0, 0), NREZ - 1);
        const int u1c = min(u0 + 1, NREZ - 1);
        const int v0c = min(max(v0, 0), NREZ - 1);
        const int v1c = min(v0 + 1, NREZ - 1);

        if (MODE <= 1) {
            // each pixel is 8 floats = 2 float4; issue all 8 loads, then FMA
            const int i00 = ((v0c << 8) + u0c) * 2;
            const int i10 = ((v0c << 8) + u1c) * 2;
            const int i01 = ((v1c << 8) + u0c) * 2;
            const int i11 = ((v1c << 8) + u1c) * 2;
            const float4 A = base4[i00], B = base4[i00 + 1];
            const float4 C = base4[i10], D = base4[i10 + 1];
            const float4 E = base4[i01], F = base4[i01 + 1];
            const float4 G = base4[i11], H = base4[i11 + 1];
            fma4(accLo, w00, A); fma4(accHi, w00, B);
            fma4(accLo, w10, C); fma4(accHi, w10, D);
            fma4(accLo, w01, E); fma4(accHi, w01, F);
            fma4(accLo, w11, G); fma4(accHi, w11, H);
        } else {
            const int a00 = v0c * NREZ + u0c;
            const int a10 = v0c * NREZ + u1c;
            const int a01 = v1c * NREZ + u0c;
            const int a11 = v1c * NREZ + u1c;
#pragma unroll
            for (int b = 0; b < NB; ++b) {
                const float* p = imgPlain + b * (NREZ * NREZ);
                accP[b] += w00 * p[a00] + w10 * p[a10] + w01 * p[a01] + w11 * p[a11];
            }
        }
    }

    float res[NB];
    if (MODE <= 1) {
        res[0] = accLo.x; res[1] = accLo.y; res[2] = accLo.z; res[3] = accLo.w;
        res[4] = accHi.x; res[5] = accHi.y; res[6] = accHi.z; res[7] = accHi.w;
    } else {
#pragma unroll
        for (int b = 0; b < NB; ++b) res[b] = accP[b];
    }

    // reduce across t-phase lanes (lane bits 3..5)
#pragma unroll
    for (int b = 0; b < NB; ++b) {
        float v = res[b];
        v += __shfl_xor(v, 8);
        v += __shfl_xor(v, 16);
        v += __shfl_xor(v, 32);
        res[b] = v;
    }

    if (t_sub == 0) {
#pragma unroll
        for (int b = 0; b < NB; ++b) {
            out[(b * NA + a) * NREZ + sIdx] = res[b];
        }
    }
}

extern "C" void kernel_launch(void* const* d_in, const int* in_sizes, int n_in,
                              void* d_out, int out_size, void* d_ws, size_t ws_size,
                              hipStream_t stream) {
    (void)in_sizes; (void)n_in; (void)out_size;
    const float* imgs = (const float*)d_in[0];
    const float* angles = (const float*)d_in[1];
    float* out = (float*)d_out;

    const size_t oneCopy = (size_t)NB * NREZ * NREZ * sizeof(float);  // 2 MB
    int mode;
    if (ws_size >= 2 * oneCopy) mode = 0;
    else if (ws_size >= oneCopy) mode = 1;
    else mode = 2;

    float* inter = (float*)d_ws;
    float* interT = inter + (size_t)NB * NREZ * NREZ;

    if (mode <= 1) {
        build_interleaved<<<NREZ * NREZ / 256, 256, 0, stream>>>(
            imgs, inter, mode == 0 ? interT : inter, mode == 0 ? 1 : 0);
    }

    dim3 grid(NA, NREZ / 32);
    if (mode == 0) {
        radon_kernel<0><<<grid, 256, 0, stream>>>(imgs, (const float4*)inter,
                                                  (const float4*)interT, angles, out);
    } else if (mode == 1) {
        radon_kernel<1><<<grid, 256, 0, stream>>>(imgs, (const float4*)inter,
                                                  (const float4*)inter, angles, out);
    } else {
        radon_kernel<2><<<grid, 256, 0, stream>>>(imgs, (const float4*)imgs,
                                                  (const float4*)imgs, angles, out);
    }
}

// Round 3
// 115.853 us; speedup vs baseline: 2.9264x; 1.0824x over previous
//
#include <hip/hip_runtime.h>
#include <hip/hip_fp16.h>

#define NREZ 256
#define NB 8
#define NA 180

// padded fp16 layout: two arrays (batches 0-3, 4-7), pixel = 4 fp16 = 8B,
// row stride 272 px, 258 rows, 1-px zero guard border at (0,*) and (*,0)
#define PXS 272
#define ROWS 258
#define PXB 8
#define ROWB (PXS * PXB)         /* 2176 B — fits 13-bit imm offset */
#define ARRB ((size_t)ROWS * PXS * PXB) /* 561408 B per array */

__device__ __forceinline__ __half2 bc_h2(unsigned int v) {
    return __builtin_bit_cast(__half2, v);
}

// one thread per pixel: interleave + convert + place at guard offset (+1,+1)
__global__ __launch_bounds__(256) void build_fp16(const float* __restrict__ img,
                                                  char* __restrict__ ws) {
    const int p = blockIdx.x * 256 + threadIdx.x;  // p = y*256 + x
    const int y = p >> 8, x = p & 255;
    float v[NB];
#pragma unroll
    for (int b = 0; b < NB; ++b) v[b] = img[b * (NREZ * NREZ) + p];
    const size_t off = (size_t)((y + 1) * PXS + (x + 1)) * PXB;
    __half2* a0 = (__half2*)(ws + off);
    __half2* a1 = (__half2*)(ws + ARRB + off);
    a0[0] = __halves2half2(__float2half_rn(v[0]), __float2half_rn(v[1]));
    a0[1] = __halves2half2(__float2half_rn(v[2]), __float2half_rn(v[3]));
    a1[0] = __halves2half2(__float2half_rn(v[4]), __float2half_rn(v[5]));
    a1[1] = __halves2half2(__float2half_rn(v[6]), __float2half_rn(v[7]));
}

__global__ __launch_bounds__(256) void radon_fp16(const char* __restrict__ ws,
                                                  const float* __restrict__ angles,
                                                  float* __restrict__ out) {
    const int a = blockIdx.x;
    const int tid = threadIdx.x;
    const int wave = tid >> 6;
    const int lane = tid & 63;
    const int s_sub = lane & 7;   // 8 s fast
    const int t_sub = lane >> 3;  // 8 t phases (t stride 1 inside patch)
    const int sIdx = blockIdx.y * 32 + wave * 8 + s_sub;

    const float c = 127.5f;
    float sn, cs;
    sincosf(angles[a], &sn, &cs);
    const float s = (float)sIdx - c;
    const float xs = fmaf(s, cs, c);   // x = xs - tt*sn
    const float ys = fmaf(s, sn, c);   // y = ys + tt*cs
    const float tt0 = (float)t_sub - c;

    const char* __restrict__ A0 = ws;
    const char* __restrict__ A1 = ws + ARRB;

    float accf[NB];
#pragma unroll
    for (int b = 0; b < NB; ++b) accf[b] = 0.f;

    const __half2 hz = __float2half2_rn(0.f);

    for (int jo = 0; jo < 8; ++jo) {
        __half2 acc01 = hz, acc23 = hz, acc45 = hz, acc67 = hz;
#pragma unroll
        for (int ji = 0; ji < 4; ++ji) {
            const float tt = tt0 + (float)(8 * (jo * 4 + ji));
            const float x = fmaf(tt, -sn, xs);
            const float y = fmaf(tt, cs, ys);
            const float xf = floorf(x), yf = floorf(y);
            const int u0 = (int)xf, v0 = (int)yf;
            if (u0 >= -1 && u0 <= 255 && v0 >= -1 && v0 <= 255) {
                const float wu = x - xf, wv = y - yf;
                const float au = 1.f - wu, av = 1.f - wv;
                const __half2 w00 = __float2half2_rn(au * av);
                const __half2 w10 = __float2half2_rn(wu * av);
                const __half2 w01 = __float2half2_rn(au * wv);
                const __half2 w11 = __float2half2_rn(wu * wv);
                const unsigned int off =
                    (unsigned int)((v0 + 1) * PXS + (u0 + 1)) * PXB;
                // each load: corner (v,u) AND (v,u+1) for 4 batches
                const uint4 r0a = *(const uint4*)(A0 + off);
                const uint4 r1a = *(const uint4*)(A0 + off + ROWB);
                const uint4 r0b = *(const uint4*)(A1 + off);
                const uint4 r1b = *(const uint4*)(A1 + off + ROWB);
                acc01 = __hfma2(w00, bc_h2(r0a.x), acc01);
                acc01 = __hfma2(w10, bc_h2(r0a.z), acc01);
                acc01 = __hfma2(w01, bc_h2(r1a.x), acc01);
                acc01 = __hfma2(w11, bc_h2(r1a.z), acc01);
                acc23 = __hfma2(w00, bc_h2(r0a.y), acc23);
                acc23 = __hfma2(w10, bc_h2(r0a.w), acc23);
                acc23 = __hfma2(w01, bc_h2(r1a.y), acc23);
                acc23 = __hfma2(w11, bc_h2(r1a.w), acc23);
                acc45 = __hfma2(w00, bc_h2(r0b.x), acc45);
                acc45 = __hfma2(w10, bc_h2(r0b.z), acc45);
                acc45 = __hfma2(w01, bc_h2(r1b.x), acc45);
                acc45 = __hfma2(w11, bc_h2(r1b.z), acc45);
                acc67 = __hfma2(w00, bc_h2(r0b.y), acc67);
                acc67 = __hfma2(w10, bc_h2(r0b.w), acc67);
                acc67 = __hfma2(w01, bc_h2(r1b.y), acc67);
                acc67 = __hfma2(w11, bc_h2(r1b.w), acc67);
            }
        }
        // flush packed fp16 partials into fp32 accumulators (bounds error)
        accf[0] += __low2float(acc01); accf[1] += __high2float(acc01);
        accf[2] += __low2float(acc23); accf[3] += __high2float(acc23);
        accf[4] += __low2float(acc45); accf[5] += __high2float(acc45);
        accf[6] += __low2float(acc67); accf[7] += __high2float(acc67);
    }

#pragma unroll
    for (int b = 0; b < NB; ++b) {
        float v = accf[b];
        v += __shfl_xor(v, 8);
        v += __shfl_xor(v, 16);
        v += __shfl_xor(v, 32);
        accf[b] = v;
    }
    if (t_sub == 0) {
#pragma unroll
        for (int b = 0; b < NB; ++b) {
            out[(b * NA + a) * NREZ + sIdx] = accf[b];
        }
    }
}

// -------- fallback (ws too small): direct fp32 gather with clamps --------
__global__ __launch_bounds__(256) void radon_plain(const float* __restrict__ img,
                                                   const float* __restrict__ angles,
                                                   float* __restrict__ out) {
    const int a = blockIdx.x;
    const int tid = threadIdx.x;
    const int wave = tid >> 6;
    const int lane = tid & 63;
    const int s_sub = lane & 7;
    const int t_sub = lane >> 3;
    const int sIdx = blockIdx.y * 32 + wave * 8 + s_sub;
    const float c = 127.5f;
    float sn, cs;
    sincosf(angles[a], &sn, &cs);
    const float s = (float)sIdx - c;
    float acc[NB];
#pragma unroll
    for (int b = 0; b < NB; ++b) acc[b] = 0.f;
    for (int j = 0; j < NREZ / 8; ++j) {
        const float tt = (float)(t_sub + 8 * j) - c;
        const float x = s * cs - tt * sn + c;
        const float y = s * sn + tt * cs + c;
        const float xf = floorf(x), yf = floorf(y);
        const int u0 = (int)xf, v0 = (int)yf;
        if (u0 < -1 || u0 >= NREZ || v0 < -1 || v0 >= NREZ) continue;
        const float wu = x - xf, wv = y - yf;
        const bool iu0 = (u0 >= 0), iu1 = (u0 + 1 <= NREZ - 1);
        const bool iv0 = (v0 >= 0), iv1 = (v0 + 1 <= NREZ - 1);
        const float w00 = (1.f - wu) * (1.f - wv) * ((iu0 && iv0) ? 1.f : 0.f);
        const float w10 = wu * (1.f - wv) * ((iu1 && iv0) ? 1.f : 0.f);
        const float w01 = (1.f - wu) * wv * ((iu0 && iv1) ? 1.f : 0.f);
        const float w11 = wu * wv * ((iu1 && iv1) ? 1.f : 0.f);
        const int u0c = min(max(u0, 0), NREZ - 1);
        const int u1c = min(u0 + 1, NREZ - 1);
        const int v0c = min(max(v0, 0), NREZ - 1);
        const int v1c = min(v0 + 1, NREZ - 1);
#pragma unroll
        for (int b = 0; b < NB; ++b) {
            const float* p = img + b * (NREZ * NREZ);
            acc[b] += w00 * p[v0c * NREZ + u0c] + w10 * p[v0c * NREZ + u1c] +
                      w01 * p[v1c * NREZ + u0c] + w11 * p[v1c * NREZ + u1c];
        }
    }
#pragma unroll
    for (int b = 0; b < NB; ++b) {
        float v = acc[b];
        v += __shfl_xor(v, 8);
        v += __shfl_xor(v, 16);
        v += __shfl_xor(v, 32);
        acc[b] = v;
    }
    if (t_sub == 0) {
#pragma unroll
        for (int b = 0; b < NB; ++b) out[(b * NA + a) * NREZ + sIdx] = acc[b];
    }
}

extern "C" void kernel_launch(void* const* d_in, const int* in_sizes, int n_in,
                              void* d_out, int out_size, void* d_ws, size_t ws_size,
                              hipStream_t stream) {
    (void)in_sizes; (void)n_in; (void)out_size;
    const float* imgs = (const float*)d_in[0];
    const float* angles = (const float*)d_in[1];
    float* out = (float*)d_out;

    const size_t need = 2 * ARRB;  // ~1.12 MB
    dim3 grid(NA, NREZ / 32);
    if (ws_size >= need) {
        char* ws = (char*)d_ws;
        hipMemsetAsync(ws, 0, need, stream);  // zero guard borders
        build_fp16<<<NREZ * NREZ / 256, 256, 0, stream>>>(imgs, ws);
        radon_fp16<<<grid, 256, 0, stream>>>(ws, angles, out);
    } else {
        radon_plain<<<grid, 256, 0, stream>>>(imgs, angles, out);
    }
}

// Round 4
// 103.263 us; speedup vs baseline: 3.2832x; 1.1219x over previous
//
#include <hip/hip_runtime.h>
#include <hip/hip_fp16.h>

#define NREZ 256
#define NB 8
#define NA 180

#define LW 49      /* LDS row stride in 16B pixels: 784B/row -> 4-bank shift, no pow2 alias */
#define LHMAX 46   /* max bbox rows: 31*(|cos|+|sin|) + 2 <= 46 */
#define MAGIC 2675u /* ceil(2^17/49): (n*MAGIC)>>17 == n/49 exactly for n < 43690 */
#define CHUNK_T 32
#define NCHUNK (NREZ / CHUNK_T)

__device__ __forceinline__ __half2 bc_h2(unsigned int v) {
    return __builtin_bit_cast(__half2, v);
}

// inter[y*256+x] = uint4 of 8 fp16: batches 0..7 of pixel (y,x)
__global__ __launch_bounds__(256) void build_fp16(const float* __restrict__ img,
                                                  uint4* __restrict__ inter) {
    const int p = blockIdx.x * 256 + threadIdx.x;
    unsigned short h[NB];
#pragma unroll
    for (int b = 0; b < NB; ++b)
        h[b] = __half_as_ushort(__float2half_rn(img[b * (NREZ * NREZ) + p]));
    uint4 v;
    v.x = (unsigned)h[0] | ((unsigned)h[1] << 16);
    v.y = (unsigned)h[2] | ((unsigned)h[3] << 16);
    v.z = (unsigned)h[4] | ((unsigned)h[5] << 16);
    v.w = (unsigned)h[6] | ((unsigned)h[7] << 16);
    inter[p] = v;
}

__global__ __launch_bounds__(256) void radon_lds(const uint4* __restrict__ img,
                                                 const float* __restrict__ angles,
                                                 float* __restrict__ out) {
    __shared__ uint4 tile[LW * LHMAX];  // 36.1 KB

    const int a = blockIdx.x;
    const int tid = threadIdx.x;
    const int wave = tid >> 6;
    const int lane = tid & 63;
    const int s_sub = lane & 7;   // 8 s per wave-patch row
    const int t_sub = lane >> 3;  // 8 t phases
    const int sIdx = blockIdx.y * 32 + wave * 8 + s_sub;

    const float C = 127.5f;
    float sn, cs;
    sincosf(angles[a], &sn, &cs);
    const float s = (float)sIdx - C;
    const float xs = fmaf(s, cs, C);  // x = fmaf(tt,-sn,xs)
    const float ys = fmaf(s, sn, C);  // y = fmaf(tt, cs,ys)

    // block-uniform s extremes, SAME fmaf chain as per-lane math (fp-monotone)
    const float s_lo = (float)(blockIdx.y * 32) - C;
    const float s_hi = s_lo + 31.f;
    const float xsl = fmaf(s_lo, cs, C), xsh = fmaf(s_hi, cs, C);
    const float ysl = fmaf(s_lo, sn, C), ysh = fmaf(s_hi, sn, C);

    float accf[NB];
#pragma unroll
    for (int b = 0; b < NB; ++b) accf[b] = 0.f;
    const __half2 hz = __float2half2_rn(0.f);

    for (int ck = 0; ck < NCHUNK; ++ck) {
        const float t_lo = (float)(ck * CHUNK_T) - C;
        const float t_hi = t_lo + 31.f;
        // bbox of all sample coords in this (32s x 32t) tile
        const float x00 = fmaf(t_lo, -sn, xsl), x01 = fmaf(t_hi, -sn, xsl);
        const float x10 = fmaf(t_lo, -sn, xsh), x11 = fmaf(t_hi, -sn, xsh);
        const float y00 = fmaf(t_lo, cs, ysl), y01 = fmaf(t_hi, cs, ysl);
        const float y10 = fmaf(t_lo, cs, ysh), y11 = fmaf(t_hi, cs, ysh);
        const int bx = (int)floorf(fminf(fminf(x00, x01), fminf(x10, x11)));
        const int by = (int)floorf(fminf(fminf(y00, y01), fminf(y10, y11)));
        int H = (int)floorf(fmaxf(fmaxf(y00, y01), fmaxf(y10, y11))) - by + 2;
        if (H > LHMAX) H = LHMAX;  // defensive; mathematically H <= 46
        const int nslots = LW * H;

        // stage bbox rows (49 px wide) into LDS; out-of-image -> zeros
#pragma unroll
        for (int k = 0; k < 9; ++k) {
            const int slot = tid + (k << 8);
            if (slot < nslots) {
                const int r = (int)(((unsigned)slot * MAGIC) >> 17);
                const int col = slot - r * LW;
                const int gx = bx + col, gy = by + r;
                uint4 v = make_uint4(0u, 0u, 0u, 0u);
                if (gx >= 0 && gx < NREZ && gy >= 0 && gy < NREZ)
                    v = img[(gy << 8) + gx];
                tile[slot] = v;
            }
        }
        __syncthreads();

        __half2 acc01 = hz, acc23 = hz, acc45 = hz, acc67 = hz;
#pragma unroll
        for (int it = 0; it < 4; ++it) {
            const float tt = t_lo + (float)(t_sub + 8 * it);
            const float x = fmaf(tt, -sn, xs);
            const float y = fmaf(tt, cs, ys);
            const float xf = floorf(x), yf = floorf(y);
            const float wu = x - xf, wv = y - yf;
            const float au = 1.f - wu, av = 1.f - wv;
            const __half2 w00 = __float2half2_rn(au * av);
            const __half2 w10 = __float2half2_rn(wu * av);
            const __half2 w01 = __float2half2_rn(au * wv);
            const __half2 w11 = __float2half2_rn(wu * wv);
            const int u0 = (int)xf - bx;   // in [0, W-2] by bbox construction
            const int v0 = (int)yf - by;   // in [0, H-2]
            const int base = v0 * LW + u0;
            const uint4 p00 = tile[base];
            const uint4 p10 = tile[base + 1];
            const uint4 p01 = tile[base + LW];
            const uint4 p11 = tile[base + LW + 1];
            acc01 = __hfma2(w00, bc_h2(p00.x), acc01);
            acc01 = __hfma2(w10, bc_h2(p10.x), acc01);
            acc01 = __hfma2(w01, bc_h2(p01.x), acc01);
            acc01 = __hfma2(w11, bc_h2(p11.x), acc01);
            acc23 = __hfma2(w00, bc_h2(p00.y), acc23);
            acc23 = __hfma2(w10, bc_h2(p10.y), acc23);
            acc23 = __hfma2(w01, bc_h2(p01.y), acc23);
            acc23 = __hfma2(w11, bc_h2(p11.y), acc23);
            acc45 = __hfma2(w00, bc_h2(p00.z), acc45);
            acc45 = __hfma2(w10, bc_h2(p10.z), acc45);
            acc45 = __hfma2(w01, bc_h2(p01.z), acc45);
            acc45 = __hfma2(w11, bc_h2(p11.z), acc45);
            acc67 = __hfma2(w00, bc_h2(p00.w), acc67);
            acc67 = __hfma2(w10, bc_h2(p10.w), acc67);
            acc67 = __hfma2(w01, bc_h2(p01.w), acc67);
            acc67 = __hfma2(w11, bc_h2(p11.w), acc67);
        }
        // flush packed fp16 partials (4 samples deep, same cadence as R3)
        accf[0] += __low2float(acc01); accf[1] += __high2float(acc01);
        accf[2] += __low2float(acc23); accf[3] += __high2float(acc23);
        accf[4] += __low2float(acc45); accf[5] += __high2float(acc45);
        accf[6] += __low2float(acc67); accf[7] += __high2float(acc67);
        __syncthreads();  // LDS reuse across chunks
    }

#pragma unroll
    for (int b = 0; b < NB; ++b) {
        float v = accf[b];
        v += __shfl_xor(v, 8);
        v += __shfl_xor(v, 16);
        v += __shfl_xor(v, 32);
        accf[b] = v;
    }
    if (t_sub == 0) {
#pragma unroll
        for (int b = 0; b < NB; ++b) {
            out[(b * NA + a) * NREZ + sIdx] = accf[b];
        }
    }
}

// -------- fallback (ws too small): direct fp32 gather with clamps --------
__global__ __launch_bounds__(256) void radon_plain(const float* __restrict__ img,
                                                   const float* __restrict__ angles,
                                                   float* __restrict__ out) {
    const int a = blockIdx.x;
    const int tid = threadIdx.x;
    const int wave = tid >> 6;
    const int lane = tid & 63;
    const int s_sub = lane & 7;
    const int t_sub = lane >> 3;
    const int sIdx = blockIdx.y * 32 + wave * 8 + s_sub;
    const float c = 127.5f;
    float sn, cs;
    sincosf(angles[a], &sn, &cs);
    const float s = (float)sIdx - c;
    float acc[NB];
#pragma unroll
    for (int b = 0; b < NB; ++b) acc[b] = 0.f;
    for (int j = 0; j < NREZ / 8; ++j) {
        const float tt = (float)(t_sub + 8 * j) - c;
        const float x = s * cs - tt * sn + c;
        const float y = s * sn + tt * cs + c;
        const float xf = floorf(x), yf = floorf(y);
        const int u0 = (int)xf, v0 = (int)yf;
        if (u0 < -1 || u0 >= NREZ || v0 < -1 || v0 >= NREZ) continue;
        const float wu = x - xf, wv = y - yf;
        const bool iu0 = (u0 >= 0), iu1 = (u0 + 1 <= NREZ - 1);
        const bool iv0 = (v0 >= 0), iv1 = (v0 + 1 <= NREZ - 1);
        const float w00 = (1.f - wu) * (1.f - wv) * ((iu0 && iv0) ? 1.f : 0.f);
        const float w10 = wu * (1.f - wv) * ((iu1 && iv0) ? 1.f : 0.f);
        const float w01 = (1.f - wu) * wv * ((iu0 && iv1) ? 1.f : 0.f);
        const float w11 = wu * wv * ((iu1 && iv1) ? 1.f : 0.f);
        const int u0c = min(max(u0, 0), NREZ - 1);
        const int u1c = min(u0 + 1, NREZ - 1);
        const int v0c = min(max(v0, 0), NREZ - 1);
        const int v1c = min(v0 + 1, NREZ - 1);
#pragma unroll
        for (int b = 0; b < NB; ++b) {
            const float* p = img + b * (NREZ * NREZ);
            acc[b] += w00 * p[v0c * NREZ + u0c] + w10 * p[v0c * NREZ + u1c] +
                      w01 * p[v1c * NREZ + u0c] + w11 * p[v1c * NREZ + u1c];
        }
    }
#pragma unroll
    for (int b = 0; b < NB; ++b) {
        float v = acc[b];
        v += __shfl_xor(v, 8);
        v += __shfl_xor(v, 16);
        v += __shfl_xor(v, 32);
        acc[b] = v;
    }
    if (t_sub == 0) {
#pragma unroll
        for (int b = 0; b < NB; ++b) out[(b * NA + a) * NREZ + sIdx] = acc[b];
    }
}

extern "C" void kernel_launch(void* const* d_in, const int* in_sizes, int n_in,
                              void* d_out, int out_size, void* d_ws, size_t ws_size,
                              hipStream_t stream) {
    (void)in_sizes; (void)n_in; (void)out_size;
    const float* imgs = (const float*)d_in[0];
    const float* angles = (const float*)d_in[1];
    float* out = (float*)d_out;

    const size_t need = (size_t)NREZ * NREZ * 16;  // 1 MB interleaved fp16
    dim3 grid(NA, NREZ / 32);
    if (ws_size >= need) {
        uint4* inter = (uint4*)d_ws;
        build_fp16<<<NREZ * NREZ / 256, 256, 0, stream>>>(imgs, inter);
        radon_lds<<<grid, 256, 0, stream>>>(inter, angles, out);
    } else {
        radon_plain<<<grid, 256, 0, stream>>>(imgs, angles, out);
    }
}

// Round 5
// 101.489 us; speedup vs baseline: 3.3406x; 1.0175x over previous
//
#include <hip/hip_runtime.h>
#include <hip/hip_fp16.h>

#define NREZ 256
#define NB 8
#define NA 180

#define LW 51     /* LDS row stride in 16B pixels; 51%8==3 -> bank group (c+3r)%8:
                     distinct along rows, cols, and both diagonals (2-way = free) */
#define LH 46     /* max bbox rows: 31*(|cs|+|sn|)+2 <= 46 */
#define CHUNK_T 32
#define NCHUNK (NREZ / CHUNK_T)
#define RPW 12    /* rows staged per wave: 4 waves * 12 = 48 >= LH */

__device__ __forceinline__ __half2 bc_h2(unsigned int v) {
    return __builtin_bit_cast(__half2, v);
}

// inter[y*256+x] = uint4 of 8 fp16: batches 0..7 of pixel (y,x)
__global__ __launch_bounds__(256) void build_fp16(const float* __restrict__ img,
                                                  uint4* __restrict__ inter) {
    const int p = blockIdx.x * 256 + threadIdx.x;
    unsigned short h[NB];
#pragma unroll
    for (int b = 0; b < NB; ++b)
        h[b] = __half_as_ushort(__float2half_rn(img[b * (NREZ * NREZ) + p]));
    uint4 v;
    v.x = (unsigned)h[0] | ((unsigned)h[1] << 16);
    v.y = (unsigned)h[2] | ((unsigned)h[3] << 16);
    v.z = (unsigned)h[4] | ((unsigned)h[5] << 16);
    v.w = (unsigned)h[6] | ((unsigned)h[7] << 16);
    inter[p] = v;
}

__global__ __launch_bounds__(256) void radon_lds(const uint4* __restrict__ img,
                                                 const float* __restrict__ angles,
                                                 float* __restrict__ out) {
    __shared__ uint4 tile[LW * LH];  // 37536 B -> 4 blocks/CU

    const int a = blockIdx.x;
    const int tid = threadIdx.x;
    const int wave = tid >> 6;
    const int lane = tid & 63;
    const int s_sub = lane & 7;
    const int t_sub = lane >> 3;
    const int sIdx = blockIdx.y * 32 + wave * 8 + s_sub;

    const float C = 127.5f;
    float sn, cs;
    sincosf(angles[a], &sn, &cs);
    const float s = (float)sIdx - C;
    const float xs = fmaf(s, cs, C);  // x = fmaf(tt,-sn,xs)
    const float ys = fmaf(s, sn, C);  // y = fmaf(tt, cs,ys)

    // block-uniform s extremes; SAME fmaf chain as per-lane math (fp-monotone)
    const float s_lo = (float)(blockIdx.y * 32) - C;
    const float s_hi = s_lo + 31.f;
    const float xsl = fmaf(s_lo, cs, C), xsh = fmaf(s_hi, cs, C);
    const float ysl = fmaf(s_lo, sn, C), ysh = fmaf(s_hi, sn, C);

    // ---- bbox of chunk ck (block-uniform) ----
    auto bbox = [&](int ck, int& bx, int& by, int& H) {
        const float t_lo = (float)(ck * CHUNK_T) - C;
        const float t_hi = t_lo + 31.f;
        const float x00 = fmaf(t_lo, -sn, xsl), x01 = fmaf(t_hi, -sn, xsl);
        const float x10 = fmaf(t_lo, -sn, xsh), x11 = fmaf(t_hi, -sn, xsh);
        const float y00 = fmaf(t_lo, cs, ysl), y01 = fmaf(t_hi, cs, ysl);
        const float y10 = fmaf(t_lo, cs, ysh), y11 = fmaf(t_hi, cs, ysh);
        bx = (int)floorf(fminf(fminf(x00, x01), fminf(x10, x11)));
        by = (int)floorf(fminf(fminf(y00, y01), fminf(y10, y11)));
        int h = (int)floorf(fmaxf(fmaxf(y00, y01), fmaxf(y10, y11))) - by + 2;
        H = (h > LH) ? LH : h;
    };

    float accf[NB];
#pragma unroll
    for (int b = 0; b < NB; ++b) accf[b] = 0.f;
    const __half2 hz = __float2half2_rn(0.f);

    // ---- stage chunk 0 directly ----
    int bx, by, H;
    bbox(0, bx, by, H);
#pragma unroll
    for (int k = 0; k < RPW; ++k) {
        const int row = wave + 4 * k;
        if (row < H && lane < 48) {
            const int gx = bx + lane, gy = by + row;
            uint4 v = make_uint4(0u, 0u, 0u, 0u);
            if (gx >= 0 && gx < NREZ && gy >= 0 && gy < NREZ)
                v = img[(gy << 8) + gx];
            tile[row * LW + lane] = v;
        }
    }

    for (int ck = 0; ck < NCHUNK; ++ck) {
        __syncthreads();  // chunk ck staged

        // prefetch chunk ck+1 rows into registers (latency overlaps compute)
        int nbx = 0, nby = 0, nH = 0;
        uint4 pf[RPW];
        if (ck + 1 < NCHUNK) {
            bbox(ck + 1, nbx, nby, nH);
#pragma unroll
            for (int k = 0; k < RPW; ++k) {
                const int row = wave + 4 * k;
                pf[k] = make_uint4(0u, 0u, 0u, 0u);
                if (row < nH && lane < 48) {
                    const int gx = nbx + lane, gy = nby + row;
                    if (gx >= 0 && gx < NREZ && gy >= 0 && gy < NREZ)
                        pf[k] = img[(gy << 8) + gx];
                }
            }
        }

        // ---- sample 4 t-steps from LDS ----
        const float t_lo = (float)(ck * CHUNK_T) - C;
        __half2 acc01 = hz, acc23 = hz, acc45 = hz, acc67 = hz;
#pragma unroll
        for (int it = 0; it < 4; ++it) {
            const float tt = t_lo + (float)(t_sub + 8 * it);
            const float x = fmaf(tt, -sn, xs);
            const float y = fmaf(tt, cs, ys);
            const float xf = floorf(x), yf = floorf(y);
            const float wu = x - xf, wv = y - yf;
            const float au = 1.f - wu, av = 1.f - wv;
            const __half2 w00 = __float2half2_rn(au * av);
            const __half2 w10 = __float2half2_rn(wu * av);
            const __half2 w01 = __float2half2_rn(au * wv);
            const __half2 w11 = __float2half2_rn(wu * wv);
            const int c = (int)xf - bx;  // in [0, 45] by bbox construction
            const int r = (int)yf - by;  // in [0, H-2]
            const int base = r * LW + c;
            const uint4 p00 = tile[base];
            const uint4 p10 = tile[base + 1];
            const uint4 p01 = tile[base + LW];
            const uint4 p11 = tile[base + LW + 1];
            acc01 = __hfma2(w00, bc_h2(p00.x), acc01);
            acc01 = __hfma2(w10, bc_h2(p10.x), acc01);
            acc01 = __hfma2(w01, bc_h2(p01.x), acc01);
            acc01 = __hfma2(w11, bc_h2(p11.x), acc01);
            acc23 = __hfma2(w00, bc_h2(p00.y), acc23);
            acc23 = __hfma2(w10, bc_h2(p10.y), acc23);
            acc23 = __hfma2(w01, bc_h2(p01.y), acc23);
            acc23 = __hfma2(w11, bc_h2(p11.y), acc23);
            acc45 = __hfma2(w00, bc_h2(p00.z), acc45);
            acc45 = __hfma2(w10, bc_h2(p10.z), acc45);
            acc45 = __hfma2(w01, bc_h2(p01.z), acc45);
            acc45 = __hfma2(w11, bc_h2(p11.z), acc45);
            acc67 = __hfma2(w00, bc_h2(p00.w), acc67);
            acc67 = __hfma2(w10, bc_h2(p10.w), acc67);
            acc67 = __hfma2(w01, bc_h2(p01.w), acc67);
            acc67 = __hfma2(w11, bc_h2(p11.w), acc67);
        }
        accf[0] += __low2float(acc01); accf[1] += __high2float(acc01);
        accf[2] += __low2float(acc23); accf[3] += __high2float(acc23);
        accf[4] += __low2float(acc45); accf[5] += __high2float(acc45);
        accf[6] += __low2float(acc67); accf[7] += __high2float(acc67);

        __syncthreads();  // all reads of chunk ck done

        if (ck + 1 < NCHUNK) {
#pragma unroll
            for (int k = 0; k < RPW; ++k) {
                const int row = wave + 4 * k;
                if (row < nH && lane < 48) tile[row * LW + lane] = pf[k];
            }
            bx = nbx; by = nby;
        }
    }

#pragma unroll
    for (int b = 0; b < NB; ++b) {
        float v = accf[b];
        v += __shfl_xor(v, 8);
        v += __shfl_xor(v, 16);
        v += __shfl_xor(v, 32);
        accf[b] = v;
    }
    if (t_sub == 0) {
#pragma unroll
        for (int b = 0; b < NB; ++b) {
            out[(b * NA + a) * NREZ + sIdx] = accf[b];
        }
    }
}

// -------- fallback (ws too small): direct fp32 gather with clamps --------
__global__ __launch_bounds__(256) void radon_plain(const float* __restrict__ img,
                                                   const float* __restrict__ angles,
                                                   float* __restrict__ out) {
    const int a = blockIdx.x;
    const int tid = threadIdx.x;
    const int wave = tid >> 6;
    const int lane = tid & 63;
    const int s_sub = lane & 7;
    const int t_sub = lane >> 3;
    const int sIdx = blockIdx.y * 32 + wave * 8 + s_sub;
    const float c = 127.5f;
    float sn, cs;
    sincosf(angles[a], &sn, &cs);
    const float s = (float)sIdx - c;
    float acc[NB];
#pragma unroll
    for (int b = 0; b < NB; ++b) acc[b] = 0.f;
    for (int j = 0; j < NREZ / 8; ++j) {
        const float tt = (float)(t_sub + 8 * j) - c;
        const float x = s * cs - tt * sn + c;
        const float y = s * sn + tt * cs + c;
        const float xf = floorf(x), yf = floorf(y);
        const int u0 = (int)xf, v0 = (int)yf;
        if (u0 < -1 || u0 >= NREZ || v0 < -1 || v0 >= NREZ) continue;
        const float wu = x - xf, wv = y - yf;
        const bool iu0 = (u0 >= 0), iu1 = (u0 + 1 <= NREZ - 1);
        const bool iv0 = (v0 >= 0), iv1 = (v0 + 1 <= NREZ - 1);
        const float w00 = (1.f - wu) * (1.f - wv) * ((iu0 && iv0) ? 1.f : 0.f);
        const float w10 = wu * (1.f - wv) * ((iu1 && iv0) ? 1.f : 0.f);
        const float w01 = (1.f - wu) * wv * ((iu0 && iv1) ? 1.f : 0.f);
        const float w11 = wu * wv * ((iu1 && iv1) ? 1.f : 0.f);
        const int u0c = min(max(u0, 0), NREZ - 1);
        const int u1c = min(u0 + 1, NREZ - 1);
        const int v0c = min(max(v0, 0), NREZ - 1);
        const int v1c = min(v0 + 1, NREZ - 1);
#pragma unroll
        for (int b = 0; b < NB; ++b) {
            const float* p = img + b * (NREZ * NREZ);
            acc[b] += w00 * p[v0c * NREZ + u0c] + w10 * p[v0c * NREZ + u1c] +
                      w01 * p[v1c * NREZ + u0c] + w11 * p[v1c * NREZ + u1c];
        }
    }
#pragma unroll
    for (int b = 0; b < NB; ++b) {
        float v = acc[b];
        v += __shfl_xor(v, 8);
        v += __shfl_xor(v, 16);
        v += __shfl_xor(v, 32);
        acc[b] = v;
    }
    if (t_sub == 0) {
#pragma unroll
        for (int b = 0; b < NB; ++b) out[(b * NA + a) * NREZ + sIdx] = acc[b];
    }
}

extern "C" void kernel_launch(void* const* d_in, const int* in_sizes, int n_in,
                              void* d_out, int out_size, void* d_ws, size_t ws_size,
                              hipStream_t stream) {
    (void)in_sizes; (void)n_in; (void)out_size;
    const float* imgs = (const float*)d_in[0];
    const float* angles = (const float*)d_in[1];
    float* out = (float*)d_out;

    const size_t need = (size_t)NREZ * NREZ * 16;  // 1 MB interleaved fp16
    dim3 grid(NA, NREZ / 32);
    if (ws_size >= need) {
        uint4* inter = (uint4*)d_ws;
        build_fp16<<<NREZ * NREZ / 256, 256, 0, stream>>>(imgs, inter);
        radon_lds<<<grid, 256, 0, stream>>>(inter, angles, out);
    } else {
        radon_plain<<<grid, 256, 0, stream>>>(imgs, angles, out);
    }
}

// Round 6
// 95.408 us; speedup vs baseline: 3.5535x; 1.0637x over previous
//
#include <hip/hip_runtime.h>
#include <hip/hip_fp16.h>

#define NREZ 256
#define NB 8
#define NA 180

// guarded interleaved source: 258x258 pixels of 16B (8 x fp16), 1-px zero border
#define GW 258
#define GBYTES ((size_t)GW * GW * 16)  /* 1,065,024 B */

// LDS tile: 46 rows x 72-pixel stride; row r shifted by q[r&7] pixels
#define LW 72
#define LH 46
#define QTAB 0x64317520u  /* nibble i = q[i] = {0,2,5,7,1,3,4,6}: rows/cols/diagonals all <=2-way */
#define CHUNK_T 32
#define NCHUNK (NREZ / CHUNK_T)

__device__ __forceinline__ __half2 bc_h2(unsigned int v) {
    return __builtin_bit_cast(__half2, v);
}

__device__ __forceinline__ void dma16(const uint4* g, uint4* l) {
    __builtin_amdgcn_global_load_lds(
        (const __attribute__((address_space(1))) void*)g,
        (__attribute__((address_space(3))) void*)l, 16, 0, 0);
}

// interleave 8 batches -> fp16 uint4 pixel at guard offset (+1,+1)
__global__ __launch_bounds__(256) void build_fp16g(const float* __restrict__ img,
                                                   uint4* __restrict__ gbuf) {
    const int p = blockIdx.x * 256 + threadIdx.x;  // p = y*256 + x
    const int y = p >> 8, x = p & 255;
    unsigned short h[NB];
#pragma unroll
    for (int b = 0; b < NB; ++b)
        h[b] = __half_as_ushort(__float2half_rn(img[b * (NREZ * NREZ) + p]));
    uint4 v;
    v.x = (unsigned)h[0] | ((unsigned)h[1] << 16);
    v.y = (unsigned)h[2] | ((unsigned)h[3] << 16);
    v.z = (unsigned)h[4] | ((unsigned)h[5] << 16);
    v.w = (unsigned)h[6] | ((unsigned)h[7] << 16);
    gbuf[(size_t)(y + 1) * GW + (x + 1)] = v;
}

__global__ __launch_bounds__(256) void radon_dma(const uint4* __restrict__ gbuf,
                                                 const float* __restrict__ angles,
                                                 float* __restrict__ out) {
    __shared__ uint4 tile[LW * LH];  // 52,992 B -> 3 blocks/CU

    const int a = blockIdx.x;
    const int tid = threadIdx.x;
    const int wave = tid >> 6;
    const int lane = tid & 63;
    const int s_sub = lane & 7;
    const int t_sub = lane >> 3;
    const int sIdx = blockIdx.y * 32 + wave * 8 + s_sub;

    const float C = 127.5f;
    float sn, cs;
    sincosf(angles[a], &sn, &cs);
    const float s = (float)sIdx - C;
    const float xs = fmaf(s, cs, C);  // x = fmaf(tt,-sn,xs)
    const float ys = fmaf(s, sn, C);  // y = fmaf(tt, cs,ys)

    // block-uniform s extremes; SAME fmaf chain as per-lane math (fp-monotone)
    const float s_lo = (float)(blockIdx.y * 32) - C;
    const float s_hi = s_lo + 31.f;
    const float xsl = fmaf(s_lo, cs, C), xsh = fmaf(s_hi, cs, C);
    const float ysl = fmaf(s_lo, sn, C), ysh = fmaf(s_hi, sn, C);

    // bbox of chunk ck -> clamped DMA window origin (bxs, bys)
    auto window = [&](int ck, int& bxs, int& bys) {
        const float t_lo = (float)(ck * CHUNK_T) - C;
        const float t_hi = t_lo + 31.f;
        const float x00 = fmaf(t_lo, -sn, xsl), x01 = fmaf(t_hi, -sn, xsl);
        const float x10 = fmaf(t_lo, -sn, xsh), x11 = fmaf(t_hi, -sn, xsh);
        const float y00 = fmaf(t_lo, cs, ysl), y01 = fmaf(t_hi, cs, ysl);
        const float y10 = fmaf(t_lo, cs, ysh), y11 = fmaf(t_hi, cs, ysh);
        const int bx = (int)floorf(fminf(fminf(x00, x01), fminf(x10, x11)));
        const int by = (int)floorf(fminf(fminf(y00, y01), fminf(y10, y11)));
        bxs = min(max(bx, -1), 193);  // window [bxs, bxs+63] subset of [-1, 256]
        bys = min(max(by, -1), 212);  // rows [bys, bys+45]; gy=257 skipped below
    };

    // stage all 46 rows of window (ck) via global->LDS DMA
    auto stage = [&](int bxs, int bys) {
#pragma unroll
        for (int k = 0; k < 12; ++k) {
            const int row = wave + 4 * k;                 // 0..47
            if (row < LH) {                               // wave-uniform
                const int gy = bys + row;
                if (gy <= 256) {                          // guard top: gy in [-1,256]
                    const unsigned qr = (QTAB >> ((row & 7) << 2)) & 7u;
                    const uint4* gp = gbuf + (size_t)(gy + 1) * GW + (bxs + 1) + lane;
                    dma16(gp, &tile[row * LW + qr]);
                }
            }
        }
    };

    float accf[NB];
#pragma unroll
    for (int b = 0; b < NB; ++b) accf[b] = 0.f;
    const __half2 hz = __float2half2_rn(0.f);

    int bxs, bys;
    window(0, bxs, bys);
    stage(bxs, bys);

    for (int ck = 0; ck < NCHUNK; ++ck) {
        __syncthreads();  // DMA of chunk ck drained (vmcnt(0) before barrier)

        const float t_lo = (float)(ck * CHUNK_T) - C;
        __half2 acc01 = hz, acc23 = hz, acc45 = hz, acc67 = hz;
#pragma unroll
        for (int it = 0; it < 4; ++it) {
            const float tt = t_lo + (float)(t_sub + 8 * it);
            const float x = fmaf(tt, -sn, xs);
            const float y = fmaf(tt, cs, ys);
            const float xf = floorf(x), yf = floorf(y);
            const int u0 = (int)xf, v0 = (int)yf;
            if (u0 >= -1 && u0 <= 255 && v0 >= -1 && v0 <= 255) {
                const float wu = x - xf, wv = y - yf;
                const float au = 1.f - wu, av = 1.f - wv;
                const __half2 w00 = __float2half2_rn(au * av);
                const __half2 w10 = __float2half2_rn(wu * av);
                const __half2 w01 = __float2half2_rn(au * wv);
                const __half2 w11 = __float2half2_rn(wu * wv);
                const int dx = u0 - bxs;  // in [0, 62]
                const int r = v0 - bys;   // in [0, 44]
                const unsigned qr0 = (QTAB >> ((r & 7) << 2)) & 7u;
                const unsigned qr1 = (QTAB >> (((r + 1) & 7) << 2)) & 7u;
                const int b00 = r * LW + (int)qr0 + dx;
                const int b10 = (r + 1) * LW + (int)qr1 + dx;
                const uint4 p00 = tile[b00];
                const uint4 p10 = tile[b00 + 1];
                const uint4 p01 = tile[b10];
                const uint4 p11 = tile[b10 + 1];
                acc01 = __hfma2(w00, bc_h2(p00.x), acc01);
                acc01 = __hfma2(w10, bc_h2(p10.x), acc01);
                acc01 = __hfma2(w01, bc_h2(p01.x), acc01);
                acc01 = __hfma2(w11, bc_h2(p11.x), acc01);
                acc23 = __hfma2(w00, bc_h2(p00.y), acc23);
                acc23 = __hfma2(w10, bc_h2(p10.y), acc23);
                acc23 = __hfma2(w01, bc_h2(p01.y), acc23);
                acc23 = __hfma2(w11, bc_h2(p11.y), acc23);
                acc45 = __hfma2(w00, bc_h2(p00.z), acc45);
                acc45 = __hfma2(w10, bc_h2(p10.z), acc45);
                acc45 = __hfma2(w01, bc_h2(p01.z), acc45);
                acc45 = __hfma2(w11, bc_h2(p11.z), acc45);
                acc67 = __hfma2(w00, bc_h2(p00.w), acc67);
                acc67 = __hfma2(w10, bc_h2(p10.w), acc67);
                acc67 = __hfma2(w01, bc_h2(p01.w), acc67);
                acc67 = __hfma2(w11, bc_h2(p11.w), acc67);
            }
        }
        accf[0] += __low2float(acc01); accf[1] += __high2float(acc01);
        accf[2] += __low2float(acc23); accf[3] += __high2float(acc23);
        accf[4] += __low2float(acc45); accf[5] += __high2float(acc45);
        accf[6] += __low2float(acc67); accf[7] += __high2float(acc67);

        __syncthreads();  // all reads of chunk ck done; safe to overwrite tile

        if (ck + 1 < NCHUNK) {
            window(ck + 1, bxs, bys);
            stage(bxs, bys);
        }
    }

#pragma unroll
    for (int b = 0; b < NB; ++b) {
        float v = accf[b];
        v += __shfl_xor(v, 8);
        v += __shfl_xor(v, 16);
        v += __shfl_xor(v, 32);
        accf[b] = v;
    }
    if (t_sub == 0) {
#pragma unroll
        for (int b = 0; b < NB; ++b) {
            out[(b * NA + a) * NREZ + sIdx] = accf[b];
        }
    }
}

// -------- fallback (ws too small): direct fp32 gather with clamps --------
__global__ __launch_bounds__(256) void radon_plain(const float* __restrict__ img,
                                                   const float* __restrict__ angles,
                                                   float* __restrict__ out) {
    const int a = blockIdx.x;
    const int tid = threadIdx.x;
    const int wave = tid >> 6;
    const int lane = tid & 63;
    const int s_sub = lane & 7;
    const int t_sub = lane >> 3;
    const int sIdx = blockIdx.y * 32 + wave * 8 + s_sub;
    const float c = 127.5f;
    float sn, cs;
    sincosf(angles[a], &sn, &cs);
    const float s = (float)sIdx - c;
    float acc[NB];
#pragma unroll
    for (int b = 0; b < NB; ++b) acc[b] = 0.f;
    for (int j = 0; j < NREZ / 8; ++j) {
        const float tt = (float)(t_sub + 8 * j) - c;
        const float x = s * cs - tt * sn + c;
        const float y = s * sn + tt * cs + c;
        const float xf = floorf(x), yf = floorf(y);
        const int u0 = (int)xf, v0 = (int)yf;
        if (u0 < -1 || u0 >= NREZ || v0 < -1 || v0 >= NREZ) continue;
        const float wu = x - xf, wv = y - yf;
        const bool iu0 = (u0 >= 0), iu1 = (u0 + 1 <= NREZ - 1);
        const bool iv0 = (v0 >= 0), iv1 = (v0 + 1 <= NREZ - 1);
        const float w00 = (1.f - wu) * (1.f - wv) * ((iu0 && iv0) ? 1.f : 0.f);
        const float w10 = wu * (1.f - wv) * ((iu1 && iv0) ? 1.f : 0.f);
        const float w01 = (1.f - wu) * wv * ((iu0 && iv1) ? 1.f : 0.f);
        const float w11 = wu * wv * ((iu1 && iv1) ? 1.f : 0.f);
        const int u0c = min(max(u0, 0), NREZ - 1);
        const int u1c = min(u0 + 1, NREZ - 1);
        const int v0c = min(max(v0, 0), NREZ - 1);
        const int v1c = min(v0 + 1, NREZ - 1);
#pragma unroll
        for (int b = 0; b < NB; ++b) {
            const float* p = img + b * (NREZ * NREZ);
            acc[b] += w00 * p[v0c * NREZ + u0c] + w10 * p[v0c * NREZ + u1c] +
                      w01 * p[v1c * NREZ + u0c] + w11 * p[v1c * NREZ + u1c];
        }
    }
#pragma unroll
    for (int b = 0; b < NB; ++b) {
        float v = acc[b];
        v += __shfl_xor(v, 8);
        v += __shfl_xor(v, 16);
        v += __shfl_xor(v, 32);
        acc[b] = v;
    }
    if (t_sub == 0) {
#pragma unroll
        for (int b = 0; b < NB; ++b) out[(b * NA + a) * NREZ + sIdx] = acc[b];
    }
}

extern "C" void kernel_launch(void* const* d_in, const int* in_sizes, int n_in,
                              void* d_out, int out_size, void* d_ws, size_t ws_size,
                              hipStream_t stream) {
    (void)in_sizes; (void)n_in; (void)out_size;
    const float* imgs = (const float*)d_in[0];
    const float* angles = (const float*)d_in[1];
    float* out = (float*)d_out;

    dim3 grid(NA, NREZ / 32);
    if (ws_size >= GBYTES) {
        uint4* gbuf = (uint4*)d_ws;
        hipMemsetAsync(gbuf, 0, GBYTES, stream);  // zero guard border
        build_fp16g<<<NREZ * NREZ / 256, 256, 0, stream>>>(imgs, gbuf);
        radon_dma<<<grid, 256, 0, stream>>>(gbuf, angles, out);
    } else {
        radon_plain<<<grid, 256, 0, stream>>>(imgs, angles, out);
    }
}

// Round 7
// 94.312 us; speedup vs baseline: 3.5948x; 1.0116x over previous
//
#include <hip/hip_runtime.h>
#include <hip/hip_fp16.h>

#define NREZ 256
#define NB 8
#define NA 180

// guarded interleaved source: 258x258 pixels of 16B (8 x fp16), 1-px zero border
#define GW 258
#define GBYTES ((size_t)GW * GW * 16)  /* 1,065,024 B */

// LDS tile: 46 rows x 72-pixel stride; row r shifted by q[r&7] pixels
#define LW 72
#define LH 46
#define QTAB 0x64317520u /* nibble i = q[i] = {0,2,5,7,1,3,4,6} */
// byte i = q[i] | q[(i+1)&7]<<4  -> one lookup yields q[r&7] and q[(r+1)&7]
#define QPTAB 0x0664433117755220ull
#define CHUNK_T 32
#define NCHUNK (NREZ / CHUNK_T)

__device__ __forceinline__ __half2 bc_h2(unsigned int v) {
    return __builtin_bit_cast(__half2, v);
}

__device__ __forceinline__ void dma16(const uint4* g, uint4* l) {
    __builtin_amdgcn_global_load_lds(
        (const __attribute__((address_space(1))) void*)g,
        (__attribute__((address_space(3))) void*)l, 16, 0, 0);
}

// interleave 8 batches -> fp16 uint4 pixel at guard offset (+1,+1); border rows/cols -> 0
__global__ __launch_bounds__(256) void build_fp16g(const float* __restrict__ img,
                                                   uint4* __restrict__ gbuf) {
    const int gy = blockIdx.x;  // 0..257
    for (int gx = threadIdx.x; gx < GW; gx += 256) {
        uint4 v = make_uint4(0u, 0u, 0u, 0u);
        const int x = gx - 1, y = gy - 1;
        if (x >= 0 && x < NREZ && y >= 0 && y < NREZ) {
            const int p = (y << 8) + x;
            unsigned short h[NB];
#pragma unroll
            for (int b = 0; b < NB; ++b)
                h[b] = __half_as_ushort(__float2half_rn(img[b * (NREZ * NREZ) + p]));
            v.x = (unsigned)h[0] | ((unsigned)h[1] << 16);
            v.y = (unsigned)h[2] | ((unsigned)h[3] << 16);
            v.z = (unsigned)h[4] | ((unsigned)h[5] << 16);
            v.w = (unsigned)h[6] | ((unsigned)h[7] << 16);
        }
        gbuf[(size_t)gy * GW + gx] = v;
    }
}

__global__ __launch_bounds__(256) void radon_dma(const uint4* __restrict__ gbuf,
                                                 const float* __restrict__ angles,
                                                 float* __restrict__ out) {
    __shared__ uint4 tile[LW * LH];  // 52,992 B -> 3 blocks/CU

    const int a = blockIdx.x;
    const int tid = threadIdx.x;
    const int wave = tid >> 6;
    const int lane = tid & 63;
    const int s_sub = lane & 7;
    const int t_sub = lane >> 3;
    const int sIdx = blockIdx.y * 32 + wave * 8 + s_sub;

    const float C = 127.5f;
    float sn, cs;
    sincosf(angles[a], &sn, &cs);
    const float s = (float)sIdx - C;
    const float xs = fmaf(s, cs, C);  // x = fmaf(tt,-sn,xs)
    const float ys = fmaf(s, sn, C);  // y = fmaf(tt, cs,ys)

    // block-uniform s extremes; SAME fmaf chain as per-lane math (fp-monotone)
    const float s_lo = (float)(blockIdx.y * 32) - C;
    const float s_hi = s_lo + 31.f;
    const float xsl = fmaf(s_lo, cs, C), xsh = fmaf(s_hi, cs, C);
    const float ysl = fmaf(s_lo, sn, C), ysh = fmaf(s_hi, sn, C);

    // bbox of chunk ck -> DMA window origin + interior/width classification
    auto window = [&](int ck, int& bxs, int& bys, bool& interior, int& wl) {
        const float t_lo = (float)(ck * CHUNK_T) - C;
        const float t_hi = t_lo + 31.f;
        const float x00 = fmaf(t_lo, -sn, xsl), x01 = fmaf(t_hi, -sn, xsl);
        const float x10 = fmaf(t_lo, -sn, xsh), x11 = fmaf(t_hi, -sn, xsh);
        const float y00 = fmaf(t_lo, cs, ysl), y01 = fmaf(t_hi, cs, ysl);
        const float y10 = fmaf(t_lo, cs, ysh), y11 = fmaf(t_hi, cs, ysh);
        const int bx = (int)floorf(fminf(fminf(x00, x01), fminf(x10, x11)));
        const int by = (int)floorf(fminf(fminf(y00, y01), fminf(y10, y11)));
        bxs = min(max(bx, -1), 193);  // window cols [bxs, bxs+63] subset of [-1, 256]
        bys = min(max(by, -1), 212);  // rows [bys, bys+45]; gy=257 skipped in stage
        interior = (bx >= 0) && (by >= 0) && (bx + 46 <= 255) && (by + 46 <= 255);
        wl = (bx >= -1 && bx <= 193) ? 48 : 64;  // unclamped window: 47 px used
    };

    auto stage = [&](int bxs, int bys, int wl) {
#pragma unroll
        for (int k = 0; k < 12; ++k) {
            const int row = wave + 4 * k;  // 0..47
            if (row < LH) {                // wave-uniform
                const int gy = bys + row;
                if (gy <= 256 && lane < wl) {
                    const unsigned qr = (QTAB >> ((row & 7) << 2)) & 7u;
                    const uint4* gp = gbuf + (size_t)(gy + 1) * GW + (bxs + 1) + lane;
                    dma16(gp, &tile[row * LW + qr]);
                }
            }
        }
    };

    float accf[NB];
#pragma unroll
    for (int b = 0; b < NB; ++b) accf[b] = 0.f;
    const __half2 hz = __float2half2_rn(0.f);

    int bxs, bys, wl;
    bool interior;
    window(0, bxs, bys, interior, wl);
    stage(bxs, bys, wl);

    for (int ck = 0; ck < NCHUNK; ++ck) {
        __syncthreads();  // DMA of chunk ck drained

        const float t_lo = (float)(ck * CHUNK_T) - C;
        __half2 acc01 = hz, acc23 = hz, acc45 = hz, acc67 = hz;

        auto samp = [&](float tt, bool chk) {
            const float x = fmaf(tt, -sn, xs);
            const float y = fmaf(tt, cs, ys);
            const float xf = floorf(x), yf = floorf(y);
            const int u0 = (int)xf, v0 = (int)yf;
            if (!chk || (u0 >= -1 && u0 <= 255 && v0 >= -1 && v0 <= 255)) {
                const float wu = x - xf, wv = y - yf;
                const float au = 1.f - wu, av = 1.f - wv;
                const __half2 w00 = __float2half2_rn(au * av);
                const __half2 w10 = __float2half2_rn(wu * av);
                const __half2 w01 = __float2half2_rn(au * wv);
                const __half2 w11 = __float2half2_rn(wu * wv);
                const int dx = u0 - bxs;  // in [0, 62]
                const int r = v0 - bys;   // in [0, 44]
                const unsigned pp = (unsigned)(QPTAB >> ((r & 7) << 3));
                const int b00 = r * LW + (int)(pp & 7u) + dx;
                const int b10 = (r + 1) * LW + (int)((pp >> 4) & 7u) + dx;
                const uint4 p00 = tile[b00];
                const uint4 p10 = tile[b00 + 1];
                const uint4 p01 = tile[b10];
                const uint4 p11 = tile[b10 + 1];
                acc01 = __hfma2(w00, bc_h2(p00.x), acc01);
                acc01 = __hfma2(w10, bc_h2(p10.x), acc01);
                acc01 = __hfma2(w01, bc_h2(p01.x), acc01);
                acc01 = __hfma2(w11, bc_h2(p11.x), acc01);
                acc23 = __hfma2(w00, bc_h2(p00.y), acc23);
                acc23 = __hfma2(w10, bc_h2(p10.y), acc23);
                acc23 = __hfma2(w01, bc_h2(p01.y), acc23);
                acc23 = __hfma2(w11, bc_h2(p11.y), acc23);
                acc45 = __hfma2(w00, bc_h2(p00.z), acc45);
                acc45 = __hfma2(w10, bc_h2(p10.z), acc45);
                acc45 = __hfma2(w01, bc_h2(p01.z), acc45);
                acc45 = __hfma2(w11, bc_h2(p11.z), acc45);
                acc67 = __hfma2(w00, bc_h2(p00.w), acc67);
                acc67 = __hfma2(w10, bc_h2(p10.w), acc67);
                acc67 = __hfma2(w01, bc_h2(p01.w), acc67);
                acc67 = __hfma2(w11, bc_h2(p11.w), acc67);
            }
        };

        if (interior) {
#pragma unroll
            for (int it = 0; it < 4; ++it)
                samp(t_lo + (float)(t_sub + 8 * it), false);
        } else {
#pragma unroll
            for (int it = 0; it < 4; ++it)
                samp(t_lo + (float)(t_sub + 8 * it), true);
        }

        accf[0] += __low2float(acc01); accf[1] += __high2float(acc01);
        accf[2] += __low2float(acc23); accf[3] += __high2float(acc23);
        accf[4] += __low2float(acc45); accf[5] += __high2float(acc45);
        accf[6] += __low2float(acc67); accf[7] += __high2float(acc67);

        __syncthreads();  // all reads of chunk ck done; safe to overwrite tile

        if (ck + 1 < NCHUNK) {
            window(ck + 1, bxs, bys, interior, wl);
            stage(bxs, bys, wl);
        }
    }

#pragma unroll
    for (int b = 0; b < NB; ++b) {
        float v = accf[b];
        v += __shfl_xor(v, 8);
        v += __shfl_xor(v, 16);
        v += __shfl_xor(v, 32);
        accf[b] = v;
    }
    if (t_sub == 0) {
#pragma unroll
        for (int b = 0; b < NB; ++b) {
            out[(b * NA + a) * NREZ + sIdx] = accf[b];
        }
    }
}

// -------- fallback (ws too small): direct fp32 gather with clamps --------
__global__ __launch_bounds__(256) void radon_plain(const float* __restrict__ img,
                                                   const float* __restrict__ angles,
                                                   float* __restrict__ out) {
    const int a = blockIdx.x;
    const int tid = threadIdx.x;
    const int wave = tid >> 6;
    const int lane = tid & 63;
    const int s_sub = lane & 7;
    const int t_sub = lane >> 3;
    const int sIdx = blockIdx.y * 32 + wave * 8 + s_sub;
    const float c = 127.5f;
    float sn, cs;
    sincosf(angles[a], &sn, &cs);
    const float s = (float)sIdx - c;
    float acc[NB];
#pragma unroll
    for (int b = 0; b < NB; ++b) acc[b] = 0.f;
    for (int j = 0; j < NREZ / 8; ++j) {
        const float tt = (float)(t_sub + 8 * j) - c;
        const float x = s * cs - tt * sn + c;
        const float y = s * sn + tt * cs + c;
        const float xf = floorf(x), yf = floorf(y);
        const int u0 = (int)xf, v0 = (int)yf;
        if (u0 < -1 || u0 >= NREZ || v0 < -1 || v0 >= NREZ) continue;
        const float wu = x - xf, wv = y - yf;
        const bool iu0 = (u0 >= 0), iu1 = (u0 + 1 <= NREZ - 1);
        const bool iv0 = (v0 >= 0), iv1 = (v0 + 1 <= NREZ - 1);
        const float w00 = (1.f - wu) * (1.f - wv) * ((iu0 && iv0) ? 1.f : 0.f);
        const float w10 = wu * (1.f - wv) * ((iu1 && iv0) ? 1.f : 0.f);
        const float w01 = (1.f - wu) * wv * ((iu0 && iv1) ? 1.f : 0.f);
        const float w11 = wu * wv * ((iu1 && iv1) ? 1.f : 0.f);
        const int u0c = min(max(u0, 0), NREZ - 1);
        const int u1c = min(u0 + 1, NREZ - 1);
        const int v0c = min(max(v0, 0), NREZ - 1);
        const int v1c = min(v0 + 1, NREZ - 1);
#pragma unroll
        for (int b = 0; b < NB; ++b) {
            const float* p = img + b * (NREZ * NREZ);
            acc[b] += w00 * p[v0c * NREZ + u0c] + w10 * p[v0c * NREZ + u1c] +
                      w01 * p[v1c * NREZ + u0c] + w11 * p[v1c * NREZ + u1c];
        }
    }
#pragma unroll
    for (int b = 0; b < NB; ++b) {
        float v = acc[b];
        v += __shfl_xor(v, 8);
        v += __shfl_xor(v, 16);
        v += __shfl_xor(v, 32);
        acc[b] = v;
    }
    if (t_sub == 0) {
#pragma unroll
        for (int b = 0; b < NB; ++b) out[(b * NA + a) * NREZ + sIdx] = acc[b];
    }
}

extern "C" void kernel_launch(void* const* d_in, const int* in_sizes, int n_in,
                              void* d_out, int out_size, void* d_ws, size_t ws_size,
                              hipStream_t stream) {
    (void)in_sizes; (void)n_in; (void)out_size;
    const float* imgs = (const float*)d_in[0];
    const float* angles = (const float*)d_in[1];
    float* out = (float*)d_out;

    dim3 grid(NA, NREZ / 32);
    if (ws_size >= GBYTES) {
        uint4* gbuf = (uint4*)d_ws;
        build_fp16g<<<GW, 256, 0, stream>>>(imgs, gbuf);  // fused guard-zeroing
        radon_dma<<<grid, 256, 0, stream>>>(gbuf, angles, out);
    } else {
        radon_plain<<<grid, 256, 0, stream>>>(imgs, angles, out);
    }
}